// Round 5
// baseline (321.054 us; speedup 1.0000x reference)
//
#include <hip/hip_runtime.h>
#include <hip/hip_bf16.h>

// ---------------------------------------------------------------------------
// Problem: N=2, S=2048, C=1024, A=1024, H=16, d=64, MAXLEN=2048
// Outputs: y [2,2048,1024] fp32  then  attn [2,16,2048,2048] fp32 (concat flat)
// ---------------------------------------------------------------------------

typedef __attribute__((ext_vector_type(8))) short s16x8;   // 8 x bf16 bits (4 VGPR)
typedef __attribute__((ext_vector_type(4))) float f32x4;   // MFMA acc

#define NEGV (-1e30f)
#define K1   0.1803368801111244f   /* 0.125 * log2(e) */

static __device__ __forceinline__ short f2bf(float f) {
  unsigned u = __float_as_uint(f);
  unsigned r = (u + 0x7fffu + ((u >> 16) & 1u)) >> 16;
  return (short)r;
}
static __device__ __forceinline__ float bf2f(short s) {
  return __uint_as_float(((unsigned)(unsigned short)s) << 16);
}

// async global->LDS, 16B per lane; lds dest wave-uniform (HW adds lane*16)
static __device__ __forceinline__ void gload_lds16(const void* g, void* l) {
  __builtin_amdgcn_global_load_lds(
      (const __attribute__((address_space(1))) void*)g,
      (__attribute__((address_space(3))) void*)l, 16, 0, 0);
}

// counted-vmcnt barrier (T4): N = #VMEM instrs issued after the loads we need.
// Never drains attn stores beyond necessity; lgkmcnt(0) gives LDS visibility.
template<int N>
static __device__ __forceinline__ void sync_counted() {
  __builtin_amdgcn_sched_barrier(0);
  if constexpr (N == 0)
    asm volatile("s_waitcnt vmcnt(0) lgkmcnt(0)" ::: "memory");
  else
    asm volatile("s_waitcnt vmcnt(8) lgkmcnt(0)" ::: "memory");
  __builtin_amdgcn_s_barrier();
  __builtin_amdgcn_sched_barrier(0);
}

// swizzled frag read: LDS rows of 64 shorts (128B), XOR bank-swizzle (T2)
static __device__ __forceinline__ s16x8 fragr(const short* buf, int row, int colsh) {
  int byte = row * 128 + (((colsh * 2) ^ ((row & 7) << 4)));
  return *(const s16x8*)((const char*)buf + byte);
}

// stage a 64x64 bf16 tile (ld in shorts) into swizzled-linear LDS (4096 shorts)
// source col pre-swizzled so linear gload_lds dest matches fragr's XOR (m173).
static __device__ __forceinline__ void stage64(const short* g, int ld, short* lds,
                                               int wave, int lane) {
  int jr = lane >> 3;
  int jc = ((lane & 7) ^ jr) * 8;    // swizzled short-col
  #pragma unroll
  for (int it = 0; it < 2; ++it) {
    int chunk = wave * 2 + it;       // 0..7, 8 rows each
    gload_lds16(&g[(size_t)(chunk * 8 + jr) * ld + jc], &lds[chunk * 512]);
  }
}

// ---------------- elementwise cast fp32 -> bf16 ----------------------------
__global__ void cast_f32_bf16(const float* __restrict__ in, short* __restrict__ out, int n) {
  int i = (blockIdx.x * 256 + threadIdx.x) * 8;
  if (i >= n) return;
  float4 a = *(const float4*)&in[i];
  float4 b = *(const float4*)&in[i + 4];
  s16x8 v;
  v[0] = f2bf(a.x); v[1] = f2bf(a.y); v[2] = f2bf(a.z); v[3] = f2bf(a.w);
  v[4] = f2bf(b.x); v[5] = f2bf(b.y); v[6] = f2bf(b.z); v[7] = f2bf(b.w);
  *(s16x8*)&out[i] = v;
}

// ---------------- transpose + cast: [R][Cc] fp32 -> [Cc][R] bf16 -----------
__global__ void transpose_cast(const float* __restrict__ in, short* __restrict__ out,
                               int R, int Cc) {
  __shared__ float tile[32][33];
  int c0 = blockIdx.x * 32, r0 = blockIdx.y * 32;
  int tx = threadIdx.x, ty = threadIdx.y;          // block (32,8)
  for (int i = 0; i < 32; i += 8)
    tile[ty + i][tx] = in[(size_t)(r0 + ty + i) * Cc + c0 + tx];
  __syncthreads();
  for (int i = 0; i < 32; i += 8)
    out[(size_t)(c0 + ty + i) * R + r0 + tx] = f2bf(tile[tx][ty + i]);
}

// -------- rel_table [2048][16] fp32 -> [16][2048] bf16, scaled by log2e ----
__global__ void transpose_table_k(const float* __restrict__ in, short* __restrict__ out) {
  int i = blockIdx.x * 256 + threadIdx.x;
  if (i >= 2048 * 16) return;
  int l = i >> 4, h = i & 15;
  out[h * 2048 + l] = f2bf(in[i] * 1.4426950408889634f);
}

// ---------------- mask [2][2048] int -> 64 u64 bitwords --------------------
__global__ void mask_pack(const int* __restrict__ mask, unsigned long long* __restrict__ mkb) {
  int g = blockIdx.x * 256 + threadIdx.x;          // 0..4095
  unsigned long long b = __ballot(mask[g] != 0);
  if ((threadIdx.x & 63) == 0) mkb[g >> 6] = b;
}

// ---------------- V pre-transpose: qkv V-part -> VT[n][vcol][s] bf16 -------
__global__ void vt_transpose(const short* __restrict__ qkv, short* __restrict__ vt) {
  __shared__ short tile[32][33];
  int nn = blockIdx.z;
  int c0 = blockIdx.y * 32;                        // v-col (= h*64+dd)
  int r0 = blockIdx.x * 32;                        // s
  int tx = threadIdx.x, ty = threadIdx.y;          // block (32,8)
  for (int i = 0; i < 32; i += 8)
    tile[ty + i][tx] = qkv[(size_t)(nn * 2048 + r0 + ty + i) * 3072 + 2048 + c0 + tx];
  __syncthreads();
  for (int i = 0; i < 32; i += 8)
    vt[(size_t)(nn * 1024 + c0 + ty + i) * 2048 + r0 + tx] = tile[tx][ty + i];
}

// ---------------- bf16 MFMA GEMM (m97 structure): C = A * BT^T -------------
template<bool OUT_F32>
__global__ __launch_bounds__(256) void gemm_bt(
    const short* __restrict__ A, const short* __restrict__ BT,
    void* __restrict__ Cout, int M, int Nn, int K)
{
  __shared__ short As[128 * 64];
  __shared__ short Bs[128 * 64];
  int bn = blockIdx.x, bm = blockIdx.y;
  int tid = threadIdx.x, wave = tid >> 6, lane = tid & 63;
  int wr = wave >> 1, wc = wave & 1;
  int lc = lane & 15, lg = lane >> 4;
  f32x4 acc[4][4];
  for (int i = 0; i < 4; ++i)
    for (int j = 0; j < 4; ++j) acc[i][j] = (f32x4){0.f, 0.f, 0.f, 0.f};
  const short* Abase = A  + (size_t)(bm * 128) * K;
  const short* Bbase = BT + (size_t)(bn * 128) * K;
  int srow = lane >> 3;
  int scol = (lane & 7) * 8;
  for (int k0 = 0; k0 < K; k0 += 64) {
    __syncthreads();
    #pragma unroll
    for (int it = 0; it < 4; ++it) {
      int chunk = it * 4 + wave;
      int grow = chunk * 8 + srow;
      gload_lds16(&Abase[(size_t)grow * K + k0 + scol], &As[chunk * 512]);
      gload_lds16(&Bbase[(size_t)grow * K + k0 + scol], &Bs[chunk * 512]);
    }
    __syncthreads();
    #pragma unroll
    for (int ks = 0; ks < 2; ++ks) {
      s16x8 af[4], bfr[4];
      #pragma unroll
      for (int mi = 0; mi < 4; ++mi)
        af[mi] = *(const s16x8*)&As[(wr * 64 + mi * 16 + lc) * 64 + ks * 32 + lg * 8];
      #pragma unroll
      for (int ni = 0; ni < 4; ++ni)
        bfr[ni] = *(const s16x8*)&Bs[(wc * 64 + ni * 16 + lc) * 64 + ks * 32 + lg * 8];
      #pragma unroll
      for (int mi = 0; mi < 4; ++mi)
        #pragma unroll
        for (int ni = 0; ni < 4; ++ni)
          acc[mi][ni] = __builtin_amdgcn_mfma_f32_16x16x32_bf16(af[mi], bfr[ni], acc[mi][ni], 0, 0, 0);
    }
  }
  int row0 = bm * 128 + wr * 64, col0 = bn * 128 + wc * 64;
  for (int mi = 0; mi < 4; ++mi)
    for (int ni = 0; ni < 4; ++ni)
      for (int r = 0; r < 4; ++r) {
        int row = row0 + mi * 16 + lg * 4 + r;
        int col = col0 + ni * 16 + lc;
        if constexpr (OUT_F32)
          ((float*)Cout)[(size_t)row * Nn + col] = acc[mi][ni][r];
        else
          ((short*)Cout)[(size_t)row * Nn + col] = f2bf(acc[mi][ni][r]);
      }
}

// ---------------- GEMM variant: 128x64 tile (for y = y_ws @ WoutT) ---------
__global__ __launch_bounds__(256) void gemm_bt64(
    const short* __restrict__ A, const short* __restrict__ BT,
    float* __restrict__ Cout, int M, int Nn, int K)
{
  __shared__ short As[128 * 64];
  __shared__ short Bs[64 * 64];
  int bn = blockIdx.x, bm = blockIdx.y;
  int tid = threadIdx.x, wave = tid >> 6, lane = tid & 63;
  int wr = wave >> 1, wc = wave & 1;
  int lc = lane & 15, lg = lane >> 4;
  f32x4 acc[4][2];
  for (int i = 0; i < 4; ++i)
    for (int j = 0; j < 2; ++j) acc[i][j] = (f32x4){0.f, 0.f, 0.f, 0.f};
  const short* Abase = A  + (size_t)(bm * 128) * K;
  const short* Bbase = BT + (size_t)(bn * 64) * K;
  int srow = lane >> 3;
  int scol = (lane & 7) * 8;
  for (int k0 = 0; k0 < K; k0 += 64) {
    __syncthreads();
    #pragma unroll
    for (int it = 0; it < 4; ++it) {
      int chunk = it * 4 + wave;
      gload_lds16(&Abase[(size_t)(chunk * 8 + srow) * K + k0 + scol], &As[chunk * 512]);
    }
    #pragma unroll
    for (int it = 0; it < 2; ++it) {
      int chunk = it * 4 + wave;
      if (chunk < 8)
        gload_lds16(&Bbase[(size_t)(chunk * 8 + srow) * K + k0 + scol], &Bs[chunk * 512]);
    }
    __syncthreads();
    #pragma unroll
    for (int ks = 0; ks < 2; ++ks) {
      s16x8 af[4], bfr[2];
      #pragma unroll
      for (int mi = 0; mi < 4; ++mi)
        af[mi] = *(const s16x8*)&As[(wr * 64 + mi * 16 + lc) * 64 + ks * 32 + lg * 8];
      #pragma unroll
      for (int ni = 0; ni < 2; ++ni)
        bfr[ni] = *(const s16x8*)&Bs[(wc * 32 + ni * 16 + lc) * 64 + ks * 32 + lg * 8];
      #pragma unroll
      for (int mi = 0; mi < 4; ++mi)
        #pragma unroll
        for (int ni = 0; ni < 2; ++ni)
          acc[mi][ni] = __builtin_amdgcn_mfma_f32_16x16x32_bf16(af[mi], bfr[ni], acc[mi][ni], 0, 0, 0);
    }
  }
  int row0 = bm * 128 + wr * 64, col0 = bn * 64 + wc * 32;
  for (int mi = 0; mi < 4; ++mi)
    for (int ni = 0; ni < 2; ++ni)
      for (int r = 0; r < 4; ++r)
        Cout[(size_t)(row0 + mi * 16 + lg * 4 + r) * Nn + col0 + ni * 16 + lc] = acc[mi][ni][r];
}

// ---------------- fused attention: QBLK=128, max-free 2-sweep softmax ------
// grid 512: xcd = bid&7, nh = xcd + 8*(j>>4), qt = 15-(j&15) desc (LPT).
// 4 waves; each wave owns 2 q-strips of 16 rows (s*64 + wave*16 + lc).
// Swapped QK^T: lane owns q-row; 4 consecutive k per acc reg -> float4 stores.
// K/V via gload_lds (swizzled source, T2) + counted vmcnt(8) (T4): attn
// stores never drained in-loop. Softmax is max-free (|logit|<~3 in log2 dom).
__global__ __launch_bounds__(256, 3) void attn_fused(
    const short* __restrict__ qkv,     // [4096][3072] bf16
    const short* __restrict__ vt,      // [2][1024][2048] bf16 (V^T)
    const unsigned long long* __restrict__ mkb,  // [2][32]
    const short* __restrict__ tabS,    // [16][2048] bf16, *log2e
    float* __restrict__ attn_out,      // [2][16][2048][2048]
    short* __restrict__ y_ws)          // [4096][1024] bf16
{
  int bid = blockIdx.x;
  int xcd = bid & 7, j = bid >> 3;
  int nh = xcd + 8 * (j >> 4);
  int qt = 15 - (j & 15);              // 128-row q-tile, desc for LPT
  int n = nh >> 4, h = nh & 15;
  int tid = threadIdx.x, wave = tid >> 6, lane = tid & 63;
  int lc = lane & 15, lg = lane >> 4, lg4 = lg * 4;

  __shared__ short Qs[128 * 64];       // Q, then P (wave-local strips)
  __shared__ short Ks[2 * 64 * 64];
  __shared__ short Vs[2 * 64 * 64];
  __shared__ short btab[2048];

  for (int i = tid; i < 2048; i += 256) btab[i] = tabS[h * 2048 + i];

  const short* qbase  = qkv + (size_t)(n * 2048 + qt * 128) * 3072 + h * 64;
  const short* kbase0 = qkv + (size_t)(n * 2048) * 3072 + 1024 + h * 64;
  const short* vtbase = vt + (size_t)(n * 1024 + h * 64) * 2048;
  const unsigned long long* mw = mkb + n * 32;
  float* aout = attn_out + (size_t)(n * 16 + h) * 2048 * 2048;

  // prologue: Q (16 chunks swizzled) + K0
  {
    int jr = lane >> 3;
    int jc = ((lane & 7) ^ jr) * 8;
    #pragma unroll
    for (int it = 0; it < 4; ++it) {
      int chunk = wave * 4 + it;
      gload_lds16(&qbase[(size_t)(chunk * 8 + jr) * 3072 + jc], &Qs[chunk * 512]);
    }
  }
  stage64(kbase0, 3072, &Ks[0], wave, lane);
  __syncthreads();

  s16x8 aq[2][2];                      // [strip][ks]
  #pragma unroll
  for (int s = 0; s < 2; ++s)
    #pragma unroll
    for (int ks = 0; ks < 2; ++ks)
      aq[s][ks] = fragr(Qs, s * 64 + wave * 16 + lc, ks * 32 + lg * 8);

  int qrow0 = qt * 128 + wave * 16 + lc;        // strip 0 (block-local)
  int qrow1 = qrow0 + 64;                       // strip 1
  bool qv0 = ((mw[qrow0 >> 6] >> (qrow0 & 63)) & 1ull) != 0;
  bool qv1 = ((mw[qrow1 >> 6] >> (qrow1 & 63)) & 1ull) != 0;
  int NT = 2 * qt + 2;                          // k-tiles needed
  float l0 = 0.f, l1 = 0.f;

  // ---------------- sweep 1: row sums (max-free) ----------------
  for (int kt = 0; kt < NT; ++kt) {
    int cur = kt & 1;
    sync_counted<0>();                          // own K(kt) loads done; all waves
    if (kt + 1 < NT)
      stage64(kbase0 + (size_t)(kt + 1) * 64 * 3072, 3072, &Ks[(cur ^ 1) * 4096], wave, lane);
    __builtin_amdgcn_sched_barrier(0);

    f32x4 c0[4], c1[4];
    __builtin_amdgcn_s_setprio(1);
    #pragma unroll
    for (int ni = 0; ni < 4; ++ni) {
      c0[ni] = (f32x4){0.f, 0.f, 0.f, 0.f};
      c1[ni] = (f32x4){0.f, 0.f, 0.f, 0.f};
      #pragma unroll
      for (int ks = 0; ks < 2; ++ks) {
        s16x8 kf = fragr(&Ks[cur * 4096], ni * 16 + lc, ks * 32 + lg * 8);
        c0[ni] = __builtin_amdgcn_mfma_f32_16x16x32_bf16(kf, aq[0][ks], c0[ni], 0, 0, 0);
        c1[ni] = __builtin_amdgcn_mfma_f32_16x16x32_bf16(kf, aq[1][ks], c1[ni], 0, 0, 0);
      }
    }
    __builtin_amdgcn_s_setprio(0);

    unsigned long long w = mw[kt];
    int lim0 = qrow0 - kt * 64, lim1 = qrow1 - kt * 64;
    #pragma unroll
    for (int ni = 0; ni < 4; ++ni)
      #pragma unroll
      for (int r = 0; r < 4; ++r) {
        int idx = ni * 16 + lg4 + r;
        bool bit = ((w >> idx) & 1ull) != 0;
        float b0 = bf2f(btab[lim0 - idx]);      // negative idx -> garbage, masked
        float b1 = bf2f(btab[lim1 - idx]);
        float v0 = (bit && idx <= lim0) ? fmaf(c0[ni][r], K1, b0) : NEGV;
        float v1 = (bit && idx <= lim1) ? fmaf(c1[ni][r], K1, b1) : NEGV;
        l0 += exp2f(v0);
        l1 += exp2f(v1);
      }
  }
  // one deferred cross-lane reduce (4 lg groups hold disjoint col quarters)
  l0 += __shfl_xor(l0, 16); l0 += __shfl_xor(l0, 32);
  l1 += __shfl_xor(l1, 16); l1 += __shfl_xor(l1, 32);
  float C0 = __log2f(l0), C1 = __log2f(l1);     // p = exp2(val - C)

  f32x4 y0[4], y1[4];
  #pragma unroll
  for (int ni = 0; ni < 4; ++ni) {
    y0[ni] = (f32x4){0.f, 0.f, 0.f, 0.f};
    y1[ni] = (f32x4){0.f, 0.f, 0.f, 0.f};
  }
  short* Ps = Qs;                               // Q LDS dead (aq in regs)

  sync_counted<0>();                            // pass-1 reads done everywhere
  stage64(kbase0, 3072, &Ks[0], wave, lane);
  stage64(vtbase, 2048, &Vs[0], wave, lane);
  __builtin_amdgcn_sched_barrier(0);

  // ---------------- sweep 2: normalized attn (float4) + PV ----------------
  for (int kt = 0; kt < NT; ++kt) {
    int cur = kt & 1;
    if (kt == 0) sync_counted<0>(); else sync_counted<8>();
    if (kt + 1 < NT) {
      stage64(kbase0 + (size_t)(kt + 1) * 64 * 3072, 3072, &Ks[(cur ^ 1) * 4096], wave, lane);
      stage64(vtbase + (size_t)(kt + 1) * 64, 2048, &Vs[(cur ^ 1) * 4096], wave, lane);
    }
    __builtin_amdgcn_sched_barrier(0);

    f32x4 c0[4], c1[4];
    __builtin_amdgcn_s_setprio(1);
    #pragma unroll
    for (int ni = 0; ni < 4; ++ni) {
      c0[ni] = (f32x4){0.f, 0.f, 0.f, 0.f};
      c1[ni] = (f32x4){0.f, 0.f, 0.f, 0.f};
      #pragma unroll
      for (int ks = 0; ks < 2; ++ks) {
        s16x8 kf = fragr(&Ks[cur * 4096], ni * 16 + lc, ks * 32 + lg * 8);
        c0[ni] = __builtin_amdgcn_mfma_f32_16x16x32_bf16(kf, aq[0][ks], c0[ni], 0, 0, 0);
        c1[ni] = __builtin_amdgcn_mfma_f32_16x16x32_bf16(kf, aq[1][ks], c1[ni], 0, 0, 0);
      }
    }
    __builtin_amdgcn_s_setprio(0);

    unsigned long long w = mw[kt];
    int lim0 = qrow0 - kt * 64, lim1 = qrow1 - kt * 64;
    #pragma unroll
    for (int ni = 0; ni < 4; ++ni) {
      float4 p40, p41;
      #pragma unroll
      for (int r = 0; r < 4; ++r) {
        int idx = ni * 16 + lg4 + r;
        bool bit = ((w >> idx) & 1ull) != 0;
        float b0 = bf2f(btab[lim0 - idx]);
        float b1 = bf2f(btab[lim1 - idx]);
        float v0 = (bit && idx <= lim0 && qv0) ? (fmaf(c0[ni][r], K1, b0) - C0) : -3.0e38f;
        float v1 = (bit && idx <= lim1 && qv1) ? (fmaf(c1[ni][r], K1, b1) - C1) : -3.0e38f;
        (&p40.x)[r] = exp2f(v0);
        (&p41.x)[r] = exp2f(v1);
      }
      *(float4*)&aout[(size_t)(qt * 128 + wave * 16 + lc) * 2048 + kt * 64 + ni * 16 + lg4] = p40;
      *(float4*)&aout[(size_t)(qt * 128 + 64 + wave * 16 + lc) * 2048 + kt * 64 + ni * 16 + lg4] = p41;
      // P -> LDS (swizzled, wave-local strips)
      unsigned a0 = (unsigned)(unsigned short)f2bf(p40.x) | ((unsigned)(unsigned short)f2bf(p40.y) << 16);
      unsigned a1 = (unsigned)(unsigned short)f2bf(p40.z) | ((unsigned)(unsigned short)f2bf(p40.w) << 16);
      unsigned b0p = (unsigned)(unsigned short)f2bf(p41.x) | ((unsigned)(unsigned short)f2bf(p41.y) << 16);
      unsigned b1p = (unsigned)(unsigned short)f2bf(p41.z) | ((unsigned)(unsigned short)f2bf(p41.w) << 16);
      int pr0 = wave * 16 + lc, pr1 = 64 + wave * 16 + lc;
      int pb0 = pr0 * 128 + ((ni * 32 + lg * 8) ^ ((pr0 & 7) << 4));
      int pb1 = pr1 * 128 + ((ni * 32 + lg * 8) ^ ((pr1 & 7) << 4));
      uint2 pk0; pk0.x = a0; pk0.y = a1;
      uint2 pk1; pk1.x = b0p; pk1.y = b1p;
      *(uint2*)((char*)Ps + pb0) = pk0;
      *(uint2*)((char*)Ps + pb1) = pk1;
    }
    // PV (P strips wave-local; compiler inserts lgkm waits)
    __builtin_amdgcn_s_setprio(1);
    #pragma unroll
    for (int ks = 0; ks < 2; ++ks) {
      s16x8 pa0 = fragr(Ps, wave * 16 + lc, ks * 32 + lg * 8);
      s16x8 pa1 = fragr(Ps, 64 + wave * 16 + lc, ks * 32 + lg * 8);
      #pragma unroll
      for (int ni = 0; ni < 4; ++ni) {
        s16x8 vfr = fragr(&Vs[cur * 4096], ni * 16 + lc, ks * 32 + lg * 8);
        y0[ni] = __builtin_amdgcn_mfma_f32_16x16x32_bf16(pa0, vfr, y0[ni], 0, 0, 0);
        y1[ni] = __builtin_amdgcn_mfma_f32_16x16x32_bf16(pa1, vfr, y1[ni], 0, 0, 0);
      }
    }
    __builtin_amdgcn_s_setprio(0);
  }

  // zero upper triangle (each attn byte written exactly once)
  int zc0 = NT * 64;
  if (zc0 < 2048) {
    float4 z4 = {0.f, 0.f, 0.f, 0.f};
    for (int rr = 0; rr < 128; ++rr) {
      float* dst = aout + (size_t)(qt * 128 + rr) * 2048;
      for (int cc = zc0 + (tid << 2); cc < 2048; cc += 1024)
        *(float4*)&dst[cc] = z4;
    }
  }

  // y store (padded-query rows: all p forced 0 -> yacc 0)
  #pragma unroll
  for (int ni = 0; ni < 4; ++ni) {
    int col = h * 64 + ni * 16 + lc;
    #pragma unroll
    for (int r = 0; r < 4; ++r) {
      size_t row0 = (size_t)(n * 2048 + qt * 128 + wave * 16 + lg4 + r);
      y_ws[row0 * 1024 + col] = f2bf(y0[ni][r]);
      y_ws[(row0 + 64) * 1024 + col] = f2bf(y1[ni][r]);
    }
  }
}

// ---------------------------------------------------------------------------
extern "C" void kernel_launch(void* const* d_in, const int* in_sizes, int n_in,
                              void* d_out, int out_size, void* d_ws, size_t ws_size,
                              hipStream_t stream)
{
  const float* x         = (const float*)d_in[0];
  const int*   mask      = (const int*)d_in[1];
  const float* W_qkv     = (const float*)d_in[4];
  const float* W_out     = (const float*)d_in[5];
  const float* rel_table = (const float*)d_in[6];

  char* ws = (char*)d_ws;
  short*  xb     = (short*)(ws);                 //  8,388,608 B (reused as vt)
  short*  WqkvT  = (short*)(ws + 8388608);       //  6,291,456 B
  short*  WoutT  = (short*)(ws + 14680064);      //  2,097,152 B
  short*  tabS   = (short*)(ws + 16777216);      //     65,536 B
  unsigned long long* mkb = (unsigned long long*)(ws + 16842752); // 512 B
  short*  qkv    = (short*)(ws + 16908288);      // 25,165,824 B
  short*  y_ws   = (short*)(ws + 42074112);      //  8,388,608 B
  short*  vt     = xb;                           // V^T, written after gemm1 reads xb

  float* y_out    = (float*)d_out;
  float* attn_out = y_out + (size_t)2 * 2048 * 1024;

  cast_f32_bf16<<<2048, 256, 0, stream>>>(x, xb, 4194304);
  transpose_cast<<<dim3(3072 / 32, 1024 / 32), dim3(32, 8), 0, stream>>>(W_qkv, WqkvT, 1024, 3072);
  transpose_cast<<<dim3(1024 / 32, 1024 / 32), dim3(32, 8), 0, stream>>>(W_out, WoutT, 1024, 1024);
  transpose_table_k<<<128, 256, 0, stream>>>(rel_table, tabS);
  mask_pack<<<16, 256, 0, stream>>>(mask, mkb);

  gemm_bt<false><<<dim3(24, 32), 256, 0, stream>>>(xb, WqkvT, (void*)qkv, 4096, 3072, 1024);

  vt_transpose<<<dim3(64, 32, 2), dim3(32, 8), 0, stream>>>(qkv, vt);

  attn_fused<<<512, 256, 0, stream>>>(qkv, vt, mkb, tabS, attn_out, y_ws);

  gemm_bt64<<<dim3(16, 32), 256, 0, stream>>>(y_ws, WoutT, y_out, 4096, 1024, 1024);
}